// Round 11
// baseline (473.381 us; speedup 1.0000x reference)
//
#include <hip/hip_runtime.h>

#define TT 512

typedef _Float16 half8 __attribute__((ext_vector_type(8)));
typedef __attribute__((ext_vector_type(4))) float floatx4;
typedef unsigned long long ull;

// raw workgroup barrier (no vmcnt/lgkmcnt drain); LDS FIFO is in-order per CU,
// validated R6-R10 (cross-parity reads stayed bit-exact across 512 steps).
#define BAR() do { __asm__ volatile("" ::: "memory"); \
                   __builtin_amdgcn_s_barrier();      \
                   __asm__ volatile("" ::: "memory"); } while (0)

__device__ __forceinline__ float fast_tanh(float z) {
    const float e = __expf(2.f * z);
    return 1.f - __fdividef(2.f, e + 1.f);
}
__device__ __forceinline__ float f4e(const float4& v, int r) {
    return (r == 0) ? v.x : (r == 1) ? v.y : (r == 2) ? v.z : v.w;
}
__device__ __forceinline__ unsigned pk16(float a, float b) {
    const unsigned ua = __builtin_bit_cast(unsigned short, (_Float16)a);
    const unsigned ub = __builtin_bit_cast(unsigned short, (_Float16)b);
    return ua | (ub << 16);
}

// ============================================================================
// Producer/consumer layer split across CUs.
// Blocks 0..127   : layer 0 for tile b. h0 recurrence via local LDS (4-wave
//                   M-split, 1 barrier/step); each step's h0 (fp16, B-frag
//                   chunk layout, 2KB) streamed to d_ws with agent-scope
//                   atomic stores (write-through -> MALL, XCD-safe).
//                   Progress counter published every 16 steps AFTER a full
//                   __syncthreads() vmcnt drain (all waves' stores complete).
// Blocks 128..255 : layer 1 for tile b-128. h1 recurrence via local LDS;
//                   h0(s) fetched with agent-scope atomic loads, prefetched
//                   one step ahead. Producer never waits on consumer ->
//                   correct under any dispatch order.
// ============================================================================
__global__ void __launch_bounds__(256, 1)
rnn2_pc(const float* __restrict__ x,
        const float* __restrict__ W_ih0, const float* __restrict__ W_hh0,
        const float* __restrict__ b_ih0, const float* __restrict__ b_hh0,
        const float* __restrict__ W_ih1, const float* __restrict__ W_hh1,
        const float* __restrict__ b_ih1, const float* __restrict__ b_hh1,
        const float* __restrict__ W_fc, const float* __restrict__ b_fc,
        float* __restrict__ out, ull* __restrict__ h0g, unsigned* __restrict__ cnt)
{
    __shared__ short hplane[2][1024];  // [parity][chunk*512 + 128q + 8n + j]
    __shared__ float red[4][16];

    const int tid = threadIdx.x;
    const int lane = tid & 63;
    const int wq = tid >> 6;   // 0..3 (M-slice)
    const int n = lane & 15;
    const int q = lane >> 4;

    const int mrow = 16 * wq + n;
    const int m4 = 16 * wq + 4 * q;
    const int rbase = 128 * q + 8 * n;
    const int wbase = (2 * wq + (q >> 1)) * 128 + 8 * n + 4 * (q & 1);

    const floatx4 zero4 = {0.f, 0.f, 0.f, 0.f};

    auto mkfrag = [&](const float* p, half8& hi) {
#pragma unroll
        for (int j = 0; j < 8; ++j) hi[j] = (_Float16)p[j];  // RTNE
    };

    if (blockIdx.x < 128) {
        // ========================= PRODUCER (layer 0) =========================
        const int tile = blockIdx.x;
        const int b0 = tile * 16;
        half8 wA[2];
#pragma unroll
        for (int k = 0; k < 2; ++k) mkfrag(W_hh0 + mrow * 64 + 32 * k + 8 * q, wA[k]);
        const float4 wih0v = *(const float4*)(W_ih0 + m4);
        float4 bv0 = *(const float4*)(b_ih0 + m4);
        { float4 t = *(const float4*)(b_hh0 + m4); bv0.x += t.x; bv0.y += t.y; bv0.z += t.z; bv0.w += t.w; }

        const float* xp = x + (long)(b0 + n) * TT;
        ull* rec = h0g + (size_t)tile * TT * 256;  // 256 ull per step record
        const int wull = wbase >> 2;

        // prologue s=0: h0(0) = tanh(x(0)Wih0 + b0)
        {
            const float xv0 = xp[0];
            float h[4];
#pragma unroll
            for (int r = 0; r < 4; ++r)
                h[r] = fast_tanh(__builtin_fmaf(xv0, f4e(wih0v, r), f4e(bv0, r)));
            uint2 u; u.x = pk16(h[0], h[1]); u.y = pk16(h[2], h[3]);
            *(uint2*)&hplane[0][wbase] = u;
            const ull ud = ((ull)u.y << 32) | u.x;
            __hip_atomic_store(rec + wull, ud, __ATOMIC_RELAXED, __HIP_MEMORY_SCOPE_AGENT);
        }
        BAR();

        float xv = xp[1], xnext = xp[2];
        for (int s = 1; s < TT; ++s) {
            const int rp = (s - 1) & 1, wp = s & 1;
            half8 b[2];
            b[0] = *(const half8*)&hplane[rp][rbase];
            b[1] = *(const half8*)&hplane[rp][rbase + 512];
            floatx4 aA = {__builtin_fmaf(xv, wih0v.x, bv0.x), __builtin_fmaf(xv, wih0v.y, bv0.y),
                          __builtin_fmaf(xv, wih0v.z, bv0.z), __builtin_fmaf(xv, wih0v.w, bv0.w)};
            floatx4 aB = zero4;
            aA = __builtin_amdgcn_mfma_f32_16x16x32_f16(wA[0], b[0], aA, 0, 0, 0);
            aB = __builtin_amdgcn_mfma_f32_16x16x32_f16(wA[1], b[1], aB, 0, 0, 0);
            float h[4];
#pragma unroll
            for (int r = 0; r < 4; ++r) h[r] = fast_tanh(aA[r] + aB[r]);
            uint2 u; u.x = pk16(h[0], h[1]); u.y = pk16(h[2], h[3]);
            *(uint2*)&hplane[wp][wbase] = u;
            const ull ud = ((ull)u.y << 32) | u.x;
            __hip_atomic_store(rec + (size_t)s * 256 + wull, ud,
                               __ATOMIC_RELAXED, __HIP_MEMORY_SCOPE_AGENT);
            xv = xnext; xnext = xp[(s + 2) & (TT - 1)];
            if ((s & 15) == 15) {
                __syncthreads();  // drains vmcnt for ALL waves -> steps <= s in MALL
                if (tid == 0)
                    __hip_atomic_store(cnt + tile, 0xC0DE0000u | (unsigned)s,
                                       __ATOMIC_RELEASE, __HIP_MEMORY_SCOPE_AGENT);
            } else {
                BAR();
            }
        }
    } else {
        // ========================= CONSUMER (layer 1) =========================
        const int tile = blockIdx.x - 128;
        const int b0 = tile * 16;
        half8 wA[2], wB[2];  // A = W_ih1, B = W_hh1
#pragma unroll
        for (int k = 0; k < 2; ++k) {
            mkfrag(W_ih1 + mrow * 64 + 32 * k + 8 * q, wA[k]);
            mkfrag(W_hh1 + mrow * 64 + 32 * k + 8 * q, wB[k]);
        }
        float4 bv1 = *(const float4*)(b_ih1 + m4);
        { float4 t = *(const float4*)(b_hh1 + m4); bv1.x += t.x; bv1.y += t.y; bv1.z += t.z; bv1.w += t.w; }
        const float4 wfcv = *(const float4*)(W_fc + m4);

        // h1(-1) = 0 at parity 1 (read by step i=0)
        for (int i = tid; i < 512; i += 256) ((int*)&hplane[1][0])[i] = 0;
        __syncthreads();

        const ull* rec = h0g + (size_t)tile * TT * 256;
        const unsigned* cp = cnt + tile;
        const int rull = rbase >> 2;

        int pub = -1;
        auto ensure = [&](int s) {
            if (pub >= s) return;
            unsigned v;
            do {
                v = __hip_atomic_load((unsigned*)cp, __ATOMIC_ACQUIRE, __HIP_MEMORY_SCOPE_AGENT);
            } while ((v & 0xFFFF0000u) != 0xC0DE0000u || (int)(v & 0xFFFFu) < s);
            pub = (int)(v & 0xFFFFu);
        };
        auto loadrec = [&](int s, half8* b) {
            ull* p = (ull*)(rec + (size_t)s * 256);
            union { ull u[2]; half8 v; } c0, c1;
            c0.u[0] = __hip_atomic_load(p + rull,       __ATOMIC_RELAXED, __HIP_MEMORY_SCOPE_AGENT);
            c0.u[1] = __hip_atomic_load(p + rull + 1,   __ATOMIC_RELAXED, __HIP_MEMORY_SCOPE_AGENT);
            c1.u[0] = __hip_atomic_load(p + 128 + rull, __ATOMIC_RELAXED, __HIP_MEMORY_SCOPE_AGENT);
            c1.u[1] = __hip_atomic_load(p + 128 + rull + 1, __ATOMIC_RELAXED, __HIP_MEMORY_SCOPE_AGENT);
            b[0] = c0.v; b[1] = c1.v;
        };

        ensure(0);
        half8 b[2];
        loadrec(0, b);
        float p = 0.f;

        for (int i = 0; i < TT; ++i) {
            half8 bn[2];
            if (i + 1 < TT) { ensure(i + 1); loadrec(i + 1, bn); }  // prefetch
            const int rp = (i + 1) & 1, wp = i & 1;
            half8 c[2];
            c[0] = *(const half8*)&hplane[rp][rbase];
            c[1] = *(const half8*)&hplane[rp][rbase + 512];
            floatx4 aA = {bv1.x, bv1.y, bv1.z, bv1.w};
            floatx4 aB = zero4;
            aA = __builtin_amdgcn_mfma_f32_16x16x32_f16(wA[0], b[0], aA, 0, 0, 0);
            aB = __builtin_amdgcn_mfma_f32_16x16x32_f16(wB[0], c[0], aB, 0, 0, 0);
            aA = __builtin_amdgcn_mfma_f32_16x16x32_f16(wA[1], b[1], aA, 0, 0, 0);
            aB = __builtin_amdgcn_mfma_f32_16x16x32_f16(wB[1], c[1], aB, 0, 0, 0);
            if (i < TT - 1) {
                float h[4];
#pragma unroll
                for (int r = 0; r < 4; ++r) h[r] = fast_tanh(aA[r] + aB[r]);
                uint2 u; u.x = pk16(h[0], h[1]); u.y = pk16(h[2], h[3]);
                *(uint2*)&hplane[wp][wbase] = u;
                b[0] = bn[0]; b[1] = bn[1];
                BAR();
            } else {
#pragma unroll
                for (int r = 0; r < 4; ++r) {
                    const float h = fast_tanh(aA[r] + aB[r]);
                    p = __builtin_fmaf(h, f4e(wfcv, r), p);
                }
            }
        }

        p += __shfl_xor(p, 16, 64);
        p += __shfl_xor(p, 32, 64);
        if (lane < 16) red[wq][lane] = p;
        __syncthreads();
        if (wq == 0 && lane < 16)
            out[b0 + lane] = red[0][lane] + red[1][lane] + red[2][lane] + red[3][lane] + b_fc[0];
    }
}

// ============================================================================
// Fallback (R10 kernel, 227 us known-good) if ws_size is too small.
// ============================================================================
__global__ void __launch_bounds__(512, 1)
rnn2_mfma(const float* __restrict__ x,
          const float* __restrict__ W_ih0, const float* __restrict__ W_hh0,
          const float* __restrict__ b_ih0, const float* __restrict__ b_hh0,
          const float* __restrict__ W_ih1, const float* __restrict__ W_hh1,
          const float* __restrict__ b_ih1, const float* __restrict__ b_hh1,
          const float* __restrict__ W_fc, const float* __restrict__ b_fc,
          float* __restrict__ out)
{
    __shared__ short h0f[2][1024];
    __shared__ short h1f[2][1024];
    __shared__ float red[4][16];

    const int tid = threadIdx.x;
    const int lane = tid & 63;
    const int w = tid >> 6;
    const int wq = w & 3;
    const bool isL0 = (w < 4);
    const int n = lane & 15;
    const int q = lane >> 4;
    const int b0 = blockIdx.x * 16;

    if (tid < 512) ((int*)&h1f[1][0])[tid] = 0;

    const int mrow = 16 * wq + n;
    const int m4 = 16 * wq + 4 * q;
    const int rbase = 128 * q + 8 * n;
    const int wbase = (2 * wq + (q >> 1)) * 128 + 8 * n + 4 * (q & 1);

    half8 wA[2], wB[2];
    auto mkfrag = [&](const float* p, half8& hi) {
#pragma unroll
        for (int j = 0; j < 8; ++j) hi[j] = (_Float16)p[j];
    };
    float4 wih0v = {0, 0, 0, 0}, bv0 = {0, 0, 0, 0}, bv1 = {0, 0, 0, 0}, wfcv = {0, 0, 0, 0};
    if (isL0) {
#pragma unroll
        for (int k = 0; k < 2; ++k) mkfrag(W_hh0 + mrow * 64 + 32 * k + 8 * q, wA[k]);
        wih0v = *(const float4*)(W_ih0 + m4);
        bv0 = *(const float4*)(b_ih0 + m4);
        { float4 t = *(const float4*)(b_hh0 + m4); bv0.x += t.x; bv0.y += t.y; bv0.z += t.z; bv0.w += t.w; }
    } else {
#pragma unroll
        for (int k = 0; k < 2; ++k) {
            mkfrag(W_ih1 + mrow * 64 + 32 * k + 8 * q, wA[k]);
            mkfrag(W_hh1 + mrow * 64 + 32 * k + 8 * q, wB[k]);
        }
        bv1 = *(const float4*)(b_ih1 + m4);
        { float4 t = *(const float4*)(b_hh1 + m4); bv1.x += t.x; bv1.y += t.y; bv1.z += t.z; bv1.w += t.w; }
        wfcv = *(const float4*)(W_fc + m4);
    }

    const float* xp = x + (long)(b0 + n) * TT;
    const floatx4 zero4 = {0.f, 0.f, 0.f, 0.f};

    auto epi_write = [&](const floatx4& A, const floatx4& B, short* pf) {
        float h[4];
#pragma unroll
        for (int r = 0; r < 4; ++r) h[r] = fast_tanh(A[r] + B[r]);
        uint2 u;
        u.x = pk16(h[0], h[1]);
        u.y = pk16(h[2], h[3]);
        *(uint2*)&pf[wbase] = u;
    };

    float xv = 0.f, xnext = 0.f;
    if (isL0) {
        const float xv0 = xp[0];
        float h[4];
#pragma unroll
        for (int r = 0; r < 4; ++r)
            h[r] = fast_tanh(__builtin_fmaf(xv0, f4e(wih0v, r), f4e(bv0, r)));
        uint2 u;
        u.x = pk16(h[0], h[1]);
        u.y = pk16(h[2], h[3]);
        *(uint2*)&h0f[0][wbase] = u;
        xv = xp[1];
        xnext = xp[2];
    }
    BAR();

    auto stepL0 = [&](int rp, int wp, float xvv) {
        half8 b[2];
#pragma unroll
        for (int k = 0; k < 2; ++k) b[k] = *(const half8*)&h0f[rp][rbase + 512 * k];
        floatx4 aA = {__builtin_fmaf(xvv, wih0v.x, bv0.x), __builtin_fmaf(xvv, wih0v.y, bv0.y),
                      __builtin_fmaf(xvv, wih0v.z, bv0.z), __builtin_fmaf(xvv, wih0v.w, bv0.w)};
        floatx4 aB = zero4;
        aA = __builtin_amdgcn_mfma_f32_16x16x32_f16(wA[0], b[0], aA, 0, 0, 0);
        aB = __builtin_amdgcn_mfma_f32_16x16x32_f16(wA[1], b[1], aB, 0, 0, 0);
        epi_write(aA, aB, &h0f[wp][0]);
    };
    auto stepL1 = [&](int rp0, int rp1, int wp1) {
        half8 b[2], c[2];
#pragma unroll
        for (int k = 0; k < 2; ++k) {
            b[k] = *(const half8*)&h0f[rp0][rbase + 512 * k];
            c[k] = *(const half8*)&h1f[rp1][rbase + 512 * k];
        }
        floatx4 aA = {bv1.x, bv1.y, bv1.z, bv1.w};
        floatx4 aB = zero4;
        aA = __builtin_amdgcn_mfma_f32_16x16x32_f16(wA[0], b[0], aA, 0, 0, 0);
        aB = __builtin_amdgcn_mfma_f32_16x16x32_f16(wB[0], c[0], aB, 0, 0, 0);
        aA = __builtin_amdgcn_mfma_f32_16x16x32_f16(wA[1], b[1], aA, 0, 0, 0);
        aB = __builtin_amdgcn_mfma_f32_16x16x32_f16(wB[1], c[1], aB, 0, 0, 0);
        epi_write(aA, aB, &h1f[wp1][0]);
    };

    for (int s = 1; s < 511; s += 2) {
        if (isL0) { stepL0(0, 1, xv); xv = xnext; xnext = xp[(s + 2) & (TT - 1)]; }
        else      { stepL1(0, 1, 0); }
        BAR();
        if (isL0) { stepL0(1, 0, xv); xv = xnext; xnext = xp[(s + 3) & (TT - 1)]; }
        else      { stepL1(1, 0, 1); }
        BAR();
    }
    if (isL0) stepL0(0, 1, xv);
    else      stepL1(0, 1, 0);
    BAR();

    float p = 0.f;
    if (!isL0) {
        half8 b[2], c[2];
#pragma unroll
        for (int k = 0; k < 2; ++k) {
            b[k] = *(const half8*)&h0f[1][rbase + 512 * k];
            c[k] = *(const half8*)&h1f[0][rbase + 512 * k];
        }
        floatx4 aA = {bv1.x, bv1.y, bv1.z, bv1.w};
        floatx4 aB = zero4;
        aA = __builtin_amdgcn_mfma_f32_16x16x32_f16(wA[0], b[0], aA, 0, 0, 0);
        aB = __builtin_amdgcn_mfma_f32_16x16x32_f16(wB[0], c[0], aB, 0, 0, 0);
        aA = __builtin_amdgcn_mfma_f32_16x16x32_f16(wA[1], b[1], aA, 0, 0, 0);
        aB = __builtin_amdgcn_mfma_f32_16x16x32_f16(wB[1], c[1], aB, 0, 0, 0);
#pragma unroll
        for (int r = 0; r < 4; ++r) {
            const float h = fast_tanh(aA[r] + aB[r]);
            p = __builtin_fmaf(h, f4e(wfcv, r), p);
        }
        p += __shfl_xor(p, 16, 64);
        p += __shfl_xor(p, 32, 64);
        if (lane < 16) red[wq][lane] = p;
    }
    __syncthreads();
    if (w == 4 && lane < 16)
        out[b0 + lane] = red[0][lane] + red[1][lane] + red[2][lane] + red[3][lane] + b_fc[0];
}

extern "C" void kernel_launch(void* const* d_in, const int* in_sizes, int n_in,
                              void* d_out, int out_size, void* d_ws, size_t ws_size,
                              hipStream_t stream) {
    const float* x     = (const float*)d_in[0];
    const float* W_ih0 = (const float*)d_in[1];
    const float* W_hh0 = (const float*)d_in[2];
    const float* b_ih0 = (const float*)d_in[3];
    const float* b_hh0 = (const float*)d_in[4];
    const float* W_ih1 = (const float*)d_in[5];
    const float* W_hh1 = (const float*)d_in[6];
    const float* b_ih1 = (const float*)d_in[7];
    const float* b_hh1 = (const float*)d_in[8];
    const float* W_fc  = (const float*)d_in[9];
    const float* b_fc  = (const float*)d_in[10];
    float* out = (float*)d_out;

    const size_t h0_bytes = (size_t)128 * TT * 2048;        // 134,217,728
    const size_t need = h0_bytes + 128 * sizeof(unsigned);  // + counters

    if (ws_size >= need) {
        ull* h0g = (ull*)d_ws;
        unsigned* cnt = (unsigned*)((char*)d_ws + h0_bytes);
        rnn2_pc<<<256, 256, 0, stream>>>(x, W_ih0, W_hh0, b_ih0, b_hh0,
                                         W_ih1, W_hh1, b_ih1, b_hh1,
                                         W_fc, b_fc, out, h0g, cnt);
    } else {
        rnn2_mfma<<<128, 512, 0, stream>>>(x, W_ih0, W_hh0, b_ih0, b_hh0,
                                           W_ih1, W_hh1, b_ih1, b_hh1,
                                           W_fc, b_fc, out);
    }
}

// Round 12
// 312.931 us; speedup vs baseline: 1.5127x; 1.5127x over previous
//
#include <hip/hip_runtime.h>

#define TT 512

typedef _Float16 half8 __attribute__((ext_vector_type(8)));
typedef __attribute__((ext_vector_type(4))) float floatx4;

// raw workgroup barrier (no vmcnt/lgkmcnt drain); LDS FIFO is in-order per CU,
// validated R6-R10 (cross-parity reads stayed bit-exact across 512 steps).
#define BAR() do { __asm__ volatile("" ::: "memory"); \
                   __builtin_amdgcn_s_barrier();      \
                   __asm__ volatile("" ::: "memory"); } while (0)

__device__ __forceinline__ float fast_tanh(float z) {
    const float e = __expf(2.f * z);
    return 1.f - __fdividef(2.f, e + 1.f);
}
__device__ __forceinline__ float f4e(const float4& v, int r) {
    return (r == 0) ? v.x : (r == 1) ? v.y : (r == 2) ? v.z : v.w;
}
__device__ __forceinline__ unsigned pk16(float a, float b) {
    const unsigned ua = __builtin_bit_cast(unsigned short, (_Float16)a);
    const unsigned ub = __builtin_bit_cast(unsigned short, (_Float16)b);
    return ua | (ub << 16);
}

// Layer-split wave specialization, S=2 M-split: 256 threads = 4 waves.
// Waves 0,1: L0 (M rows [32w,32w+32), 2 MFMA + 8 tanh + 2 b128 reads/step)
// Waves 2,3: L1 (8 MFMA + 8 tanh + 4 b128 reads/step)
// vs R10 (S=4): per-CU LDS reads halve (24->12 b128) by removing redundant
// B-fragment reads; per-lane tanh doubles but spreads 1 wave/SIMD.
// Arithmetic bit-identical to R10 (absmax signature 4.882812e-4).
// fp16 weights + fp16 h planes; one raw barrier per superstep.
__global__ void __launch_bounds__(256, 1)
rnn2_mfma(const float* __restrict__ x,
          const float* __restrict__ W_ih0, const float* __restrict__ W_hh0,
          const float* __restrict__ b_ih0, const float* __restrict__ b_hh0,
          const float* __restrict__ W_ih1, const float* __restrict__ W_hh1,
          const float* __restrict__ b_ih1, const float* __restrict__ b_hh1,
          const float* __restrict__ W_fc, const float* __restrict__ b_fc,
          float* __restrict__ out)
{
    __shared__ short h0f[2][1024];  // [parity][chunk*512 + 128q + 8n + j], fp16
    __shared__ short h1f[2][1024];
    __shared__ float red[2][16];

    const int tid = threadIdx.x;
    const int lane = tid & 63;
    const int w = tid >> 6;          // 0..3
    const int m = w & 1;             // M-half within the layer group
    const bool isL0 = (w < 2);
    const int n = lane & 15;
    const int q = lane >> 4;
    const int b0 = blockIdx.x * 16;

    // h1(-1) = 0 at parity 1 (read by L1 at s=1): 512 ints, 256 threads
    ((int*)&h1f[1][0])[tid] = 0;
    ((int*)&h1f[1][0])[tid + 256] = 0;

    const int rbase = 128 * q + 8 * n;
    // two M-tiles per wave: mt = 2m, 2m+1
    int wbase[2], mrow[2], m4[2];
#pragma unroll
    for (int t = 0; t < 2; ++t) {
        const int mt = 2 * m + t;
        mrow[t] = 16 * mt + n;
        m4[t] = 16 * mt + 4 * q;
        wbase[t] = (2 * mt + (q >> 1)) * 128 + 8 * n + 4 * (q & 1);
    }

    // ---- per-group weight fragments, single fp16 (RTNE) ----
    half8 wA[2][2], wB[2][2];  // [mt][k] ; L0: A=W_hh0 ; L1: A=W_ih1, B=W_hh1
    auto mkfrag = [&](const float* p, half8& hi) {
#pragma unroll
        for (int j = 0; j < 8; ++j) hi[j] = (_Float16)p[j];  // RTNE
    };
    float4 wih0v[2], bv0[2], bv1[2], wfcv[2];
#pragma unroll
    for (int t = 0; t < 2; ++t) {
        wih0v[t] = make_float4(0, 0, 0, 0); bv0[t] = make_float4(0, 0, 0, 0);
        bv1[t] = make_float4(0, 0, 0, 0); wfcv[t] = make_float4(0, 0, 0, 0);
    }
    if (isL0) {
#pragma unroll
        for (int t = 0; t < 2; ++t) {
#pragma unroll
            for (int k = 0; k < 2; ++k)
                mkfrag(W_hh0 + mrow[t] * 64 + 32 * k + 8 * q, wA[t][k]);
            wih0v[t] = *(const float4*)(W_ih0 + m4[t]);
            bv0[t] = *(const float4*)(b_ih0 + m4[t]);
            float4 u = *(const float4*)(b_hh0 + m4[t]);
            bv0[t].x += u.x; bv0[t].y += u.y; bv0[t].z += u.z; bv0[t].w += u.w;
        }
    } else {
#pragma unroll
        for (int t = 0; t < 2; ++t) {
#pragma unroll
            for (int k = 0; k < 2; ++k) {
                mkfrag(W_ih1 + mrow[t] * 64 + 32 * k + 8 * q, wA[t][k]);
                mkfrag(W_hh1 + mrow[t] * 64 + 32 * k + 8 * q, wB[t][k]);
            }
            bv1[t] = *(const float4*)(b_ih1 + m4[t]);
            float4 u = *(const float4*)(b_hh1 + m4[t]);
            bv1[t].x += u.x; bv1[t].y += u.y; bv1[t].z += u.z; bv1[t].w += u.w;
            wfcv[t] = *(const float4*)(W_fc + m4[t]);
        }
    }

    const float* xp = x + (long)(b0 + n) * TT;
    const floatx4 zero4 = {0.f, 0.f, 0.f, 0.f};

    // tanh + fp16 pack + LDS write for one M-tile
    auto epi_write = [&](const floatx4& A, const floatx4& B, short* pf, int t) {
        float h[4];
#pragma unroll
        for (int r = 0; r < 4; ++r) h[r] = fast_tanh(A[r] + B[r]);
        uint2 u;
        u.x = pk16(h[0], h[1]);
        u.y = pk16(h[2], h[3]);
        *(uint2*)&pf[wbase[t]] = u;
    };

    // ---- prologue: L0 waves write h0(0) = tanh(x(0)Wih0 + b0) -> parity 0 ----
    float xv = 0.f, xnext = 0.f;
    if (isL0) {
        const float xv0 = xp[0];
#pragma unroll
        for (int t = 0; t < 2; ++t) {
            float h[4];
#pragma unroll
            for (int r = 0; r < 4; ++r)
                h[r] = fast_tanh(__builtin_fmaf(xv0, f4e(wih0v[t], r), f4e(bv0[t], r)));
            uint2 u; u.x = pk16(h[0], h[1]); u.y = pk16(h[2], h[3]);
            *(uint2*)&h0f[0][wbase[t]] = u;
        }
        xv = xp[1];
        xnext = xp[2];
    }
    BAR();

    // L0 superstep: read h0[rp], compute h0(s) for both M-tiles, write h0[wp]
    auto stepL0 = [&](int rp, int wp, float xvv) {
        half8 b[2];
        b[0] = *(const half8*)&h0f[rp][rbase];
        b[1] = *(const half8*)&h0f[rp][rbase + 512];
        floatx4 aA[2], aB[2];
#pragma unroll
        for (int t = 0; t < 2; ++t) {
            aA[t] = (floatx4){__builtin_fmaf(xvv, wih0v[t].x, bv0[t].x),
                              __builtin_fmaf(xvv, wih0v[t].y, bv0[t].y),
                              __builtin_fmaf(xvv, wih0v[t].z, bv0[t].z),
                              __builtin_fmaf(xvv, wih0v[t].w, bv0[t].w)};
            aB[t] = zero4;
            aA[t] = __builtin_amdgcn_mfma_f32_16x16x32_f16(wA[t][0], b[0], aA[t], 0, 0, 0);
            aB[t] = __builtin_amdgcn_mfma_f32_16x16x32_f16(wA[t][1], b[1], aB[t], 0, 0, 0);
        }
#pragma unroll
        for (int t = 0; t < 2; ++t) epi_write(aA[t], aB[t], &h0f[wp][0], t);
    };

    // L1 superstep: read h0[rp0], h1[rp1], compute h1 for both M-tiles, write
    auto stepL1 = [&](int rp0, int rp1, int wp1) {
        half8 b[2], c[2];
        b[0] = *(const half8*)&h0f[rp0][rbase];
        b[1] = *(const half8*)&h0f[rp0][rbase + 512];
        c[0] = *(const half8*)&h1f[rp1][rbase];
        c[1] = *(const half8*)&h1f[rp1][rbase + 512];
        floatx4 aA[2], aB[2];
#pragma unroll
        for (int t = 0; t < 2; ++t) {
            aA[t] = (floatx4){bv1[t].x, bv1[t].y, bv1[t].z, bv1[t].w};
            aB[t] = zero4;
            aA[t] = __builtin_amdgcn_mfma_f32_16x16x32_f16(wA[t][0], b[0], aA[t], 0, 0, 0);
            aB[t] = __builtin_amdgcn_mfma_f32_16x16x32_f16(wB[t][0], c[0], aB[t], 0, 0, 0);
            aA[t] = __builtin_amdgcn_mfma_f32_16x16x32_f16(wA[t][1], b[1], aA[t], 0, 0, 0);
            aB[t] = __builtin_amdgcn_mfma_f32_16x16x32_f16(wB[t][1], c[1], aB[t], 0, 0, 0);
        }
#pragma unroll
        for (int t = 0; t < 2; ++t) epi_write(aA[t], aB[t], &h1f[wp1][0], t);
    };

    // main loop: pairs (s odd, s+1 even), s = 1..509; tail s = 511
    for (int s = 1; s < 511; s += 2) {
        if (isL0) {
            stepL0(0, 1, xv);
            xv = xnext; xnext = xp[(s + 2) & (TT - 1)];
        } else {
            stepL1(0, 1, 0);
        }
        BAR();
        if (isL0) {
            stepL0(1, 0, xv);
            xv = xnext; xnext = xp[(s + 3) & (TT - 1)];
        } else {
            stepL1(1, 0, 1);
        }
        BAR();
    }
    // s = 511 (odd): L0 h0(511) -> parity 1 ; L1 h1(510) -> parity 0
    if (isL0) stepL0(0, 1, xv);
    else      stepL1(0, 1, 0);
    BAR();

    // ---- tail: L1 waves compute h1(511) + FC dot ----
    float p = 0.f;
    if (!isL0) {
        half8 b[2], c[2];
        b[0] = *(const half8*)&h0f[1][rbase];        // h0(511), parity 1
        b[1] = *(const half8*)&h0f[1][rbase + 512];
        c[0] = *(const half8*)&h1f[0][rbase];        // h1(510), parity 0
        c[1] = *(const half8*)&h1f[0][rbase + 512];
#pragma unroll
        for (int t = 0; t < 2; ++t) {
            floatx4 aA = {bv1[t].x, bv1[t].y, bv1[t].z, bv1[t].w};
            floatx4 aB = zero4;
            aA = __builtin_amdgcn_mfma_f32_16x16x32_f16(wA[t][0], b[0], aA, 0, 0, 0);
            aB = __builtin_amdgcn_mfma_f32_16x16x32_f16(wB[t][0], c[0], aB, 0, 0, 0);
            aA = __builtin_amdgcn_mfma_f32_16x16x32_f16(wA[t][1], b[1], aA, 0, 0, 0);
            aB = __builtin_amdgcn_mfma_f32_16x16x32_f16(wB[t][1], c[1], aB, 0, 0, 0);
#pragma unroll
            for (int r = 0; r < 4; ++r) {
                const float h = fast_tanh(aA[r] + aB[r]);
                p = __builtin_fmaf(h, f4e(wfcv[t], r), p);
            }
        }
        p += __shfl_xor(p, 16, 64);
        p += __shfl_xor(p, 32, 64);
        if (lane < 16) red[m][lane] = p;
    }
    __syncthreads();
    if (w == 2 && lane < 16)
        out[b0 + lane] = red[0][lane] + red[1][lane] + b_fc[0];
}

extern "C" void kernel_launch(void* const* d_in, const int* in_sizes, int n_in,
                              void* d_out, int out_size, void* d_ws, size_t ws_size,
                              hipStream_t stream) {
    const float* x     = (const float*)d_in[0];
    const float* W_ih0 = (const float*)d_in[1];
    const float* W_hh0 = (const float*)d_in[2];
    const float* b_ih0 = (const float*)d_in[3];
    const float* b_hh0 = (const float*)d_in[4];
    const float* W_ih1 = (const float*)d_in[5];
    const float* W_hh1 = (const float*)d_in[6];
    const float* b_ih1 = (const float*)d_in[7];
    const float* b_hh1 = (const float*)d_in[8];
    const float* W_fc  = (const float*)d_in[9];
    const float* b_fc  = (const float*)d_in[10];
    float* out = (float*)d_out;

    rnn2_mfma<<<128, 256, 0, stream>>>(x, W_ih0, W_hh0, b_ih0, b_hh0,
                                       W_ih1, W_hh1, b_ih1, b_hh1,
                                       W_fc, b_fc, out);
}